// Round 18
// baseline (436.089 us; speedup 1.0000x reference)
//
#include <hip/hip_runtime.h>
#include <hip/hip_bf16.h>
#include <hip/hip_fp8.h>

// sim[b,l,m] = sum_d relu(prev@W+b)[b,l,d] * relu(after@W+b)[b,m,d]
// bz=16, L=2048, d=768.
//
// Pipeline:
//   1. wt_kernel : Wt[n][k] = bf16(W[k][n])                    (ws, 1.2 MB)
//   2. gemm_ff   : P8 = fp8(relu(bf16(seq) @ Wt^T + bias))     (ws, 48 MB)
//   3. gemm_sim  : sim[b] = P8p[b] @ P8a[b]^T -> fp32 d_out    (fp8 MFMA)
//
// ROUND 17 + gemm_ff-only changes (it runs at its achieved HBM rate, which
// is shallow-queue-limited at 1 block/CU):
//  (1) 3-deep A prefetch: ping-pong reg sets arA/arB (+32 VGPR, ~156 total,
//      safe at (512,2)); A(kt+3) issued at tile kt -> in-flight loads
//      12-20 (was 4-12). Ledger: prologue FWAITV(12) retires A1+B0;
//      steady FWAITV(8) retires B(kt+1)+A(kt+2) == the guarantee next
//      iter's CVT needs (old pre-CVT FWAITV(4) now dead, removed).
//      Tail walked: A(11) forced at kt=9, B(11) at kt=10's FWAITV(0).
//  (2) HW bf16 cvt (__bf16 cast -> v_cvt_pk_bf16_f32; m240) replaces the
//      3-op bit-twiddle in the critical CVT section. RNE == RNE, absmax 4.0.
// gemm_sim byte-identical to round 17 (223.5-225us proven).

typedef __attribute__((ext_vector_type(8)))  short bf16x8v;
typedef __attribute__((ext_vector_type(8)))  short s16x8;
typedef __attribute__((ext_vector_type(4)))  float f32x4;
typedef __attribute__((ext_vector_type(16))) float f32x16;
typedef __attribute__((ext_vector_type(4)))  float float4v;
typedef __attribute__((ext_vector_type(2)))  long  long2v;

__device__ __forceinline__ unsigned short f2bf(float f) {
  unsigned int u = __float_as_uint(f);
  u += 0x7fffu + ((u >> 16) & 1u);
  return (unsigned short)(u >> 16);
}

// HW path: fptrunc f32->bf16 is RNE; compiler pairs into v_cvt_pk_bf16_f32.
__device__ __forceinline__ short f2bf_hw(float f) {
  __bf16 h = (__bf16)f;
  return *reinterpret_cast<short*>(&h);
}

__device__ __forceinline__ unsigned char f2e4m3(float f) {
  __hip_fp8_e4m3 q(f);                        // OCP e4m3fn, RNE+sat
  return (unsigned char)q.__x;
}

__device__ __forceinline__ void async_copy16(void* lds, const void* g) {
  __builtin_amdgcn_global_load_lds(
      (const __attribute__((address_space(1))) void*)g,
      (__attribute__((address_space(3))) void*)lds, 16, 0, 0);
}

// proven macro set (round-5 skeleton)
#define BAR()    asm volatile("s_barrier" ::: "memory")
#define WAITV3() asm volatile("s_waitcnt vmcnt(3)" ::: "memory")
#define WAITV0() asm volatile("s_waitcnt vmcnt(0)" ::: "memory")
#define WAITL()  do { asm volatile("s_waitcnt lgkmcnt(0)" ::: "memory"); \
                      __builtin_amdgcn_sched_barrier(0); } while (0)
// pinned variants (gemm_ff)
#define FBARF()   do { __builtin_amdgcn_sched_barrier(0);                 \
                       __builtin_amdgcn_s_barrier();                      \
                       __builtin_amdgcn_sched_barrier(0); } while (0)
#define FWAITV(n) do { asm volatile("s_waitcnt vmcnt(" #n ")" ::: "memory"); \
                       __builtin_amdgcn_sched_barrier(0); } while (0)
#define FLGKM0()  do { asm volatile("s_waitcnt lgkmcnt(0)" ::: "memory");  \
                       __builtin_amdgcn_sched_barrier(0); } while (0)

// ---------------- W transpose + convert: Wt[n][k] = bf16(W[k][n]) ------------
__global__ void wt_kernel(const float* __restrict__ W, short* __restrict__ Wt) {
  int idx = blockIdx.x * 256 + threadIdx.x;   // n*768 + k
  int n = idx / 768;
  int k = idx - n * 768;
  Wt[idx] = f2bf_hw(W[k * 768 + n]);
}

// ======== gemm_ff: P8 = fp8(relu(bf16(seq) @ Wt^T + bias)), fused ===========
__global__ __launch_bounds__(512, 2)
void gemm_ff(const float* __restrict__ Sprev, const float* __restrict__ Safter,
             const short* __restrict__ Wt, const float* __restrict__ bias,
             unsigned char* __restrict__ Out) {
  constexpr int BK = 64, KT = 12;             // K = 768
  __shared__ __align__(16) short lA[2][256 * BK];
  __shared__ __align__(16) short lB[2][256 * BK];

  // T1: XCD-chunked swizzle (768 = 8 * 96, bijective).
  const int bid  = blockIdx.x;                // 0..767
  const int virt = (bid & 7) * 96 + (bid >> 3);
  const int by   = virt / 3;                  // 0..255 (M-tile)
  const int bx   = virt - by * 3;             // 0..2   (N-tile)

  const int tid  = threadIdx.x;
  const int lane = tid & 63;
  const int w    = tid >> 6;
  const int wr   = w >> 2;                    // 0..1 (M half)
  const int wc   = w & 3;                    // 0..3 (N quarter)
  const int tn   = bx * 256;                  // 0,256,512

  const float* Af = (by < 128 ? Sprev : Safter) + (size_t)((by & 127) * 256) * 768;
  const int    tm = by * 256;                 // global output row base

  const int l31  = lane & 31;
  const int khb  = (lane >> 5) * 16;
  const int sx   = ((lane >> 2) & 7) << 4;    // q = (row>>2)&7 (round-11 fix)
  const int arow = wr * 128 + l31;
  const int brow = wc * 64 + l31;

#define FF_LOAD_A(k0, AR)                                                     \
  {                                                                           \
    _Pragma("unroll")                                                         \
    for (int _q = 0; _q < 4; ++_q) {                                          \
      int _seg = _q * 512 + tid;                                              \
      int _row = _seg >> 3;                                                   \
      const float* _g = Af + (size_t)_row * 768 + (k0) + (_seg & 7) * 8;      \
      AR[2 * _q]     = *(const float4v*)_g;                                   \
      AR[2 * _q + 1] = *(const float4v*)(_g + 4);                             \
    }                                                                         \
  }

#define FF_CVT_WRITE(buf, AR)                                                 \
  {                                                                           \
    _Pragma("unroll")                                                         \
    for (int _q = 0; _q < 4; ++_q) {                                          \
      int _seg = _q * 512 + tid;                                              \
      int _row = _seg >> 3;                                                   \
      int _cb  = ((_seg & 7) * 16) ^ (((_row >> 2) & 7) << 4);                \
      s16x8 _o;                                                               \
      _o[0] = f2bf_hw(AR[2 * _q][0]);     _o[1] = f2bf_hw(AR[2 * _q][1]);     \
      _o[2] = f2bf_hw(AR[2 * _q][2]);     _o[3] = f2bf_hw(AR[2 * _q][3]);     \
      _o[4] = f2bf_hw(AR[2 * _q + 1][0]); _o[5] = f2bf_hw(AR[2 * _q + 1][1]); \
      _o[6] = f2bf_hw(AR[2 * _q + 1][2]); _o[7] = f2bf_hw(AR[2 * _q + 1][3]); \
      *(s16x8*)((char*)lA[buf] + _row * 128 + _cb) = _o;                      \
    }                                                                         \
  }

#define FF_STAGE_B(buf, k0)                                                   \
  {                                                                           \
    _Pragma("unroll")                                                         \
    for (int _j = 0; _j < 4; ++_j) {                                          \
      int _c   = _j * 512 + tid;                                              \
      int _row = _c >> 3;                                                     \
      int _cb  = ((_c & 7) * 16) ^ (((_row >> 2) & 7) << 4);                  \
      async_copy16((char*)lB[buf] + _j * 8192 + w * 1024,                     \
                   (const char*)(Wt + (size_t)(tn + _row) * 768 + (k0)) + _cb); \
    }                                                                         \
  }

#define FF_FRAGS(buf, kk)                                                     \
  {                                                                           \
    const char* _bA = (const char*)lA[buf];                                   \
    const char* _bB = (const char*)lB[buf];                                   \
    _Pragma("unroll")                                                         \
    for (int _ks = 0; _ks < 2; ++_ks) {                                       \
      const int _kx = ((kk) * 64 + _ks * 32 + khb) ^ sx;                      \
      _Pragma("unroll")                                                       \
      for (int _mt = 0; _mt < 4; ++_mt)                                       \
        af[_mt][_ks] = *(const bf16x8v*)(_bA + (arow + _mt * 32) * 128 + _kx);\
      _Pragma("unroll")                                                       \
      for (int _nt = 0; _nt < 2; ++_nt)                                       \
        bg[_nt][_ks] = *(const bf16x8v*)(_bB + (brow + _nt * 32) * 128 + _kx);\
    }                                                                         \
  }

#define FF_MFMA()                                                             \
  {                                                                           \
    __builtin_amdgcn_s_setprio(1);                                            \
    _Pragma("unroll")                                                         \
    for (int _ks = 0; _ks < 2; ++_ks)                                         \
      _Pragma("unroll")                                                       \
      for (int _mt = 0; _mt < 4; ++_mt)                                       \
        _Pragma("unroll")                                                     \
        for (int _nt = 0; _nt < 2; ++_nt)                                     \
          acc[_mt][_nt] = __builtin_amdgcn_mfma_f32_32x32x16_bf16(            \
              af[_mt][_ks], bg[_nt][_ks], acc[_mt][_nt], 0, 0, 0);            \
    __builtin_amdgcn_s_setprio(0);                                            \
  }

  f32x16 acc[4][2] = {};
  bf16x8v af[4][2], bg[2][2];
  float4v arA[8], arB[8];                     // ping-pong A reg sets

  // prologue: A(0)->arA->lA[0]; A(1)->arB; B(0),B(1) staged; A(2)->arA.
  FF_LOAD_A(0, arA);                          // vm: A0=8
  FWAITV(0);
  FF_CVT_WRITE(0, arA);                       // buf0
  FF_LOAD_A(BK, arB);                         // vm: A1=8
  FF_STAGE_B(0, 0);                           // vm: +B0=4
  FF_STAGE_B(1, BK);                          // vm: +B1=4
  FF_LOAD_A(2 * BK, arA);                     // vm: +A2=8  (out: 24)
  FLGKM0();                                   // own lA[0] writes done
  FWAITV(12);                                 // retires A1+B0 (oldest 12)
  FBARF();                                    // tile0 ready for everyone

  // A(n) lives in set n&1. At iter kt: CVT A(kt+1) from set (kt+1)&1, then
  // LOAD A(kt+3) into the same set (freed by the CVT; reg dep keeps order).
  for (int kt = 0; kt < KT; ++kt) {
    const int cur = kt & 1, nxt = cur ^ 1;
    FF_FRAGS(cur, 0);                         // 12 ds_read
    if (kt + 1 < KT) {                        // A(kt+1) landed: prior FWAITV(8)
      if ((kt + 1) & 1) { FF_CVT_WRITE(nxt, arB); }
      else              { FF_CVT_WRITE(nxt, arA); }
    }
    if (kt < KT - 3) {                        // A(kt+3) -> same-parity set
      if ((kt + 1) & 1) { FF_LOAD_A((kt + 3) * BK, arB); }
      else              { FF_LOAD_A((kt + 3) * BK, arA); }
    }
    FLGKM0();                                 // frags + writes done
    FF_MFMA();                                // kk0
    FF_FRAGS(cur, 1);                         // 12 ds_read
    FLGKM0();                                 // all reads of buf[cur] done
    if (kt + 1 < KT) {
      if (kt + 2 < KT) { FWAITV(8); }         // retires B(kt+1)+A(kt+2)
      else             { FWAITV(0); }         // tail drain
      FBARF();                                // tile kt+1 ready; buf[cur] free
      if (kt + 2 < KT) FF_STAGE_B(cur, (kt + 2) * BK);
    }
    FF_MFMA();                                // kk1
  }

  // epilogue: bias+relu -> fp8 e4m3
#pragma unroll
  for (int mt = 0; mt < 4; ++mt) {
    int rowb = tm + wr * 128 + mt * 32 + 4 * (lane >> 5);
#pragma unroll
    for (int nt = 0; nt < 2; ++nt) {
      int col = tn + wc * 64 + nt * 32 + l31;
      float bv = bias[col];
#pragma unroll
      for (int reg = 0; reg < 16; ++reg) {
        int row = rowb + (reg & 3) + 8 * (reg >> 2);
        float v = fmaxf(acc[mt][nt][reg] + bv, 0.0f);
        Out[(size_t)row * 768 + col] = f2e4m3(v);
      }
    }
  }
#undef FF_LOAD_A
#undef FF_CVT_WRITE
#undef FF_STAGE_B
#undef FF_FRAGS
#undef FF_MFMA
}

// ======== gemm_sim: sim[b] = P8p[b] @ P8a[b]^T (fp8 e4m3 MFMA) ==============
// 256x128 tile, 8 waves 4Mx2N (64x64/wave), 16x16x32 fp8 frags,
// XOR-swizzled LDS (byte ^= ((row>>1)&3)<<4, both sides), round-5 ledger.
// Dual-kk packed b128 frag reads (virtual-k permutation).
__global__ __launch_bounds__(512, 4)
void gemm_sim(const unsigned char* __restrict__ A, const unsigned char* __restrict__ B,
              float* __restrict__ C) {
  constexpr int BK = 64, KT = 12, LD = 2048;  // K = 768 (BK elems = bytes)
  __shared__ __align__(16) unsigned char lA[2][256 * BK];   // 16 KB per buf
  __shared__ __align__(16) unsigned char lB[2][128 * BK];   // 8 KB per buf

  // T1: XCD-chunked swizzle (2048 = 8 * 256, bijective).
  const int bid  = blockIdx.x;                // 0..2047
  const int virt = (bid & 7) * 256 + (bid >> 3);
  const int bz   = virt >> 7;                 // 0..15 batch
  const int rem  = virt & 127;
  const int by   = rem >> 4;                  // 0..7  M-tile (256 rows)
  const int bx   = rem & 15;                  // 0..15 N-tile (128 rows)

  const int tid  = threadIdx.x;
  const int lane = tid & 63;
  const int w    = tid >> 6;                  // 0..7
  const int wr   = w >> 1;                    // 0..3  (M quarter: 64 rows)
  const int wc   = w & 1;                     // 0..1  (N half: 64 cols)
  const int tm   = by * 256;
  const int tn   = bx * 128;

  const unsigned char* Ab = A + (size_t)bz * LD * 768 + (size_t)tm * 768;
  const unsigned char* Bb = B + (size_t)bz * LD * 768 + (size_t)tn * 768;

  const int lrow = lane & 15;                 // fragment row within 16
  const int kqb  = (lane >> 4) * 16;          // byte base of lane's dual-kk 16B
  const int arow = wr * 64 + lrow;            // A row base (0..255)
  const int brow = wc * 64 + lrow;            // B row base (0..127)
  // frag rows step by 16 -> swizzle constant per lane (hoisted):
  const int swA  = ((arow >> 1) & 3) << 4;
  const int swB  = ((brow >> 1) & 3) << 4;

  // stage one K-tile: A 16KB (2 rounds) + B 8KB (1 round), pre-swizzled src
#define STAGE(buf, k0)                                                        \
  {                                                                           \
    _Pragma("unroll")                                                         \
    for (int _j = 0; _j < 2; ++_j) {                                          \
      int _c   = _j * 512 + tid;                                              \
      int _row = _c >> 2;                                                     \
      int _cb  = ((_c & 3) * 16) ^ (((_row >> 1) & 3) << 4);                  \
      async_copy16((char*)lA[buf] + _j * 8192 + w * 1024,                     \
                   Ab + (size_t)_row * 768 + (k0) + _cb);                     \
    }                                                                         \
    {                                                                         \
      int _row = tid >> 2;                                                    \
      int _cb  = ((tid & 3) * 16) ^ (((_row >> 1) & 3) << 4);                 \
      async_copy16((char*)lB[buf] + w * 1024,                                 \
                   Bb + (size_t)_row * 768 + (k0) + _cb);                     \
    }                                                                         \
  }

  // one b128 per frag covers BOTH kk phases (virtual-k permutation):
  // bytes [q*16 .. q*16+15] = true k {q*16..+7} (kk0) ++ {q*16+8..+15} (kk1)
#define LOAD_FRAGS_ALL(buf)                                                   \
  {                                                                           \
    const char* _bA = (const char*)lA[buf];                                   \
    const char* _bB = (const char*)lB[buf];                                   \
    const int _koA = kqb ^ swA;                                               \
    const int _koB = kqb ^ swB;                                               \
    _Pragma("unroll")                                                         \
    for (int _mt = 0; _mt < 4; ++_mt)                                         \
      af[_mt] = *(const long2v*)(_bA + (arow + _mt * 16) * BK + _koA);        \
    _Pragma("unroll")                                                         \
    for (int _nt = 0; _nt < 4; ++_nt)                                         \
      bg[_nt] = *(const long2v*)(_bB + (brow + _nt * 16) * BK + _koB);        \
  }

#define MFMA_PH(h)                                                            \
  {                                                                           \
    __builtin_amdgcn_s_setprio(1);                                            \
    _Pragma("unroll")                                                         \
    for (int _mt = 0; _mt < 4; ++_mt)                                         \
      _Pragma("unroll")                                                       \
      for (int _nt = 0; _nt < 4; ++_nt)                                       \
        acc[_mt][_nt] = __builtin_amdgcn_mfma_f32_16x16x32_fp8_fp8(           \
            af[_mt][h], bg[_nt][h], acc[_mt][_nt], 0, 0, 0);                  \
    __builtin_amdgcn_s_setprio(0);                                            \
  }

  f32x4 acc[4][4] = {};
  long2v af[4], bg[4];

  STAGE(0, 0);
  STAGE(1, BK);                               // vm out: 6

  int cur = 0;
  for (int kt = 0; kt < KT; ++kt) {
    if (kt < KT - 1) { WAITV3(); } else { WAITV0(); }   // tile kt landed (own)
    BAR();                                              // landed for everyone

    LOAD_FRAGS_ALL(cur);                      // 8 ds_read_b128
    WAITL();                                  // all reads of buf[cur] done
    BAR();                                    // done for everyone -> buf free
    if (kt < KT - 2) STAGE(cur, (kt + 2) * BK);  // overlapped with MFMAs
    MFMA_PH(0);                               // 16 MFMA (kk0 = .x halves)
    MFMA_PH(1);                               // 16 MFMA (kk1 = .y halves)

    cur ^= 1;
  }

  // epilogue: 16x16 C/D layout col=lane&15, row=(lane>>4)*4+reg
  float* Cb = C + (size_t)bz * LD * LD;
#pragma unroll
  for (int mt = 0; mt < 4; ++mt) {
    int row0 = tm + wr * 64 + mt * 16 + (lane >> 4) * 4;
#pragma unroll
    for (int nt = 0; nt < 4; ++nt) {
      int col = tn + wc * 64 + nt * 16 + lrow;
#pragma unroll
      for (int i = 0; i < 4; ++i)
        Cb[(size_t)(row0 + i) * LD + col] = acc[mt][nt][i];
    }
  }
#undef STAGE
#undef LOAD_FRAGS_ALL
#undef MFMA_PH
}

extern "C" void kernel_launch(void* const* d_in, const int* in_sizes, int n_in,
                              void* d_out, int out_size, void* d_ws, size_t ws_size,
                              hipStream_t stream) {
  const float* seq_prev  = (const float*)d_in[0];  // [16][2048][768]
  const float* seq_after = (const float*)d_in[1];  // [16][2048][768]
  const float* W         = (const float*)d_in[2];  // [768][768] (in,out)
  const float* bias      = (const float*)d_in[3];  // [768]
  float* out             = (float*)d_out;          // [16][2048][2048] fp32

  char* ws           = (char*)d_ws;
  short* Wt          = (short*)ws;                 // 768*768*2 = 1179648 B
  unsigned char* P8  = (unsigned char*)(ws + 1179648);  // 65536*768 fp8 = 48 MB

  constexpr int NSEQ = 16 * 2048 * 768;            // elems (=bytes in fp8)

  // 1. W transpose + convert
  wt_kernel<<<768 * 768 / 256, 256, 0, stream>>>(W, Wt);

  // 2. feed-forward + relu -> fp8 (768 blocks, XCD-swizzled)
  gemm_ff<<<768, 512, 0, stream>>>(seq_prev, seq_after, Wt, bias, P8);

  // 3. batched similarity in fp8 (2048 blocks, XCD-swizzled)
  gemm_sim<<<2048, 512, 0, stream>>>(P8, P8 + NSEQ, out);
}

// Round 19
// 217.441 us; speedup vs baseline: 2.0055x; 2.0055x over previous
//
#include <hip/hip_runtime.h>
#include <hip/hip_bf16.h>
#include <hip/hip_fp8.h>

// sim[b,l,m] = sum_d relu(prev@W+b)[b,l,d] * relu(after@W+b)[b,m,d]
// bz=16, L=2048, d=768.
//
// Pipeline:
//   1. wt_kernel : Wt[n][k] = bf16(W[k][n])                    (ws, 1.2 MB)
//   2. gemm_ff   : P8 = fp8(relu(bf16(seq) @ Wt^T + bias))     (ws, 48 MB)
//   3. gemm_sim  : sim[b] = P8p[b] @ P8a[b]^T -> fp32 d_out
//
// ROUND 17 base (gemm_ff reverted exactly — round-18 prefetch spilled) +
// ONE CHANGE (gemm_sim): MX-scaled fp8 MFMA (mfma_scale_f32_32x32x64_f8f6f4,
// unit e8m0 scales 0x7F) — 2x the non-scaled fp8 rate (m145->m148: 1.64x).
// Same 256x128 tile / 8 waves / BK=64 / STAGE+swizzle / WAITV3 ledger;
// per K-tile now 8 ds_read_b128 (each lane: 32 contiguous k-bytes as 2x16B)
// + 4 MFMA (was 32 of 16x16x32). C/D = HW-verified 32x32 layout (as gemm_ff).
// Regs: acc 64 + frags 32 + misc ~= 120 < 128 -> (512,4) legal.

typedef __attribute__((ext_vector_type(8)))  short bf16x8v;
typedef __attribute__((ext_vector_type(8)))  short s16x8;
typedef __attribute__((ext_vector_type(4)))  float f32x4;
typedef __attribute__((ext_vector_type(16))) float f32x16;
typedef __attribute__((ext_vector_type(4)))  float float4v;
typedef __attribute__((ext_vector_type(8)))  int   int8v;
typedef __attribute__((ext_vector_type(4)))  int   int4v;

__device__ __forceinline__ unsigned short f2bf(float f) {
  unsigned int u = __float_as_uint(f);
  u += 0x7fffu + ((u >> 16) & 1u);
  return (unsigned short)(u >> 16);
}

__device__ __forceinline__ unsigned char f2e4m3(float f) {
  __hip_fp8_e4m3 q(f);                        // OCP e4m3fn, RNE+sat
  return (unsigned char)q.__x;
}

__device__ __forceinline__ void async_copy16(void* lds, const void* g) {
  __builtin_amdgcn_global_load_lds(
      (const __attribute__((address_space(1))) void*)g,
      (__attribute__((address_space(3))) void*)lds, 16, 0, 0);
}

// proven macro set (round-5 skeleton)
#define BAR()    asm volatile("s_barrier" ::: "memory")
#define WAITV3() asm volatile("s_waitcnt vmcnt(3)" ::: "memory")
#define WAITV0() asm volatile("s_waitcnt vmcnt(0)" ::: "memory")
#define WAITL()  do { asm volatile("s_waitcnt lgkmcnt(0)" ::: "memory"); \
                      __builtin_amdgcn_sched_barrier(0); } while (0)
// pinned variants (gemm_ff)
#define FBARF()   do { __builtin_amdgcn_sched_barrier(0);                 \
                       __builtin_amdgcn_s_barrier();                      \
                       __builtin_amdgcn_sched_barrier(0); } while (0)
#define FWAITV(n) do { asm volatile("s_waitcnt vmcnt(" #n ")" ::: "memory"); \
                       __builtin_amdgcn_sched_barrier(0); } while (0)
#define FLGKM0()  do { asm volatile("s_waitcnt lgkmcnt(0)" ::: "memory");  \
                       __builtin_amdgcn_sched_barrier(0); } while (0)

// ---------------- W transpose + convert: Wt[n][k] = bf16(W[k][n]) ------------
__global__ void wt_kernel(const float* __restrict__ W, short* __restrict__ Wt) {
  int idx = blockIdx.x * 256 + threadIdx.x;   // n*768 + k
  int n = idx / 768;
  int k = idx - n * 768;
  Wt[idx] = (short)f2bf(W[k * 768 + n]);
}

// ======== gemm_ff: P8 = fp8(relu(bf16(seq) @ Wt^T + bias)), fused ===========
__global__ __launch_bounds__(512, 2)
void gemm_ff(const float* __restrict__ Sprev, const float* __restrict__ Safter,
             const short* __restrict__ Wt, const float* __restrict__ bias,
             unsigned char* __restrict__ Out) {
  constexpr int BK = 64, KT = 12;             // K = 768
  __shared__ __align__(16) short lA[2][256 * BK];
  __shared__ __align__(16) short lB[2][256 * BK];

  // T1: XCD-chunked swizzle (768 = 8 * 96, bijective).
  const int bid  = blockIdx.x;                // 0..767
  const int virt = (bid & 7) * 96 + (bid >> 3);
  const int by   = virt / 3;                  // 0..255 (M-tile)
  const int bx   = virt - by * 3;             // 0..2   (N-tile)

  const int tid  = threadIdx.x;
  const int lane = tid & 63;
  const int w    = tid >> 6;
  const int wr   = w >> 2;                    // 0..1 (M half)
  const int wc   = w & 3;                     // 0..3 (N quarter)
  const int tn   = bx * 256;                  // 0,256,512

  const float* Af = (by < 128 ? Sprev : Safter) + (size_t)((by & 127) * 256) * 768;
  const int    tm = by * 256;                 // global output row base

  const int l31  = lane & 31;
  const int khb  = (lane >> 5) * 16;
  const int sx   = ((lane >> 2) & 7) << 4;    // q = (row>>2)&7 (round-11 fix)
  const int arow = wr * 128 + l31;
  const int brow = wc * 64 + l31;

#define FF_LOAD_A(k0)                                                         \
  {                                                                           \
    _Pragma("unroll")                                                         \
    for (int _q = 0; _q < 4; ++_q) {                                          \
      int _seg = _q * 512 + tid;                                              \
      int _row = _seg >> 3;                                                   \
      const float* _g = Af + (size_t)_row * 768 + (k0) + (_seg & 7) * 8;      \
      ar[2 * _q]     = *(const float4v*)_g;                                   \
      ar[2 * _q + 1] = *(const float4v*)(_g + 4);                             \
    }                                                                         \
  }

#define FF_CVT_WRITE(buf)                                                     \
  {                                                                           \
    _Pragma("unroll")                                                         \
    for (int _q = 0; _q < 4; ++_q) {                                          \
      int _seg = _q * 512 + tid;                                              \
      int _row = _seg >> 3;                                                   \
      int _cb  = ((_seg & 7) * 16) ^ (((_row >> 2) & 7) << 4);                \
      s16x8 _o;                                                               \
      _o[0] = (short)f2bf(ar[2 * _q][0]);     _o[1] = (short)f2bf(ar[2 * _q][1]); \
      _o[2] = (short)f2bf(ar[2 * _q][2]);     _o[3] = (short)f2bf(ar[2 * _q][3]); \
      _o[4] = (short)f2bf(ar[2 * _q + 1][0]); _o[5] = (short)f2bf(ar[2 * _q + 1][1]); \
      _o[6] = (short)f2bf(ar[2 * _q + 1][2]); _o[7] = (short)f2bf(ar[2 * _q + 1][3]); \
      *(s16x8*)((char*)lA[buf] + _row * 128 + _cb) = _o;                      \
    }                                                                         \
  }

#define FF_STAGE_B(buf, k0)                                                   \
  {                                                                           \
    _Pragma("unroll")                                                         \
    for (int _j = 0; _j < 4; ++_j) {                                          \
      int _c   = _j * 512 + tid;                                              \
      int _row = _c >> 3;                                                     \
      int _cb  = ((_c & 7) * 16) ^ (((_row >> 2) & 7) << 4);                  \
      async_copy16((char*)lB[buf] + _j * 8192 + w * 1024,                     \
                   (const char*)(Wt + (size_t)(tn + _row) * 768 + (k0)) + _cb); \
    }                                                                         \
  }

#define FF_FRAGS(buf, kk)                                                     \
  {                                                                           \
    const char* _bA = (const char*)lA[buf];                                   \
    const char* _bB = (const char*)lB[buf];                                   \
    _Pragma("unroll")                                                         \
    for (int _ks = 0; _ks < 2; ++_ks) {                                       \
      const int _kx = ((kk) * 64 + _ks * 32 + khb) ^ sx;                      \
      _Pragma("unroll")                                                       \
      for (int _mt = 0; _mt < 4; ++_mt)                                       \
        af[_mt][_ks] = *(const bf16x8v*)(_bA + (arow + _mt * 32) * 128 + _kx);\
      _Pragma("unroll")                                                       \
      for (int _nt = 0; _nt < 2; ++_nt)                                       \
        bg[_nt][_ks] = *(const bf16x8v*)(_bB + (brow + _nt * 32) * 128 + _kx);\
    }                                                                         \
  }

#define FF_MFMA()                                                             \
  {                                                                           \
    __builtin_amdgcn_s_setprio(1);                                            \
    _Pragma("unroll")                                                         \
    for (int _ks = 0; _ks < 2; ++_ks)                                         \
      _Pragma("unroll")                                                       \
      for (int _mt = 0; _mt < 4; ++_mt)                                       \
        _Pragma("unroll")                                                     \
        for (int _nt = 0; _nt < 2; ++_nt)                                     \
          acc[_mt][_nt] = __builtin_amdgcn_mfma_f32_32x32x16_bf16(            \
              af[_mt][_ks], bg[_nt][_ks], acc[_mt][_nt], 0, 0, 0);            \
    __builtin_amdgcn_s_setprio(0);                                            \
  }

  f32x16 acc[4][2] = {};
  bf16x8v af[4][2], bg[2][2];
  float4v ar[8];

  // prologue: A(0) -> regs -> lA[0]; A(1) -> regs; B(0),B(1) staged.
  FF_LOAD_A(0);                               // vm: A0=8
  FWAITV(0);
  FF_CVT_WRITE(0);
  FF_LOAD_A(BK);                              // vm: A1=8
  FF_STAGE_B(0, 0);                           // vm: +B0=4
  FF_STAGE_B(1, BK);                          // vm: +B1=4  (out: 16)
  FLGKM0();                                   // own lA[0] writes done
  FWAITV(4);                                  // retires A1+B0: B0 landed
  FBARF();                                    // tile0 ready for everyone

  for (int kt = 0; kt < KT; ++kt) {
    const int cur = kt & 1, nxt = cur ^ 1;
    FF_FRAGS(cur, 0);                         // 12 ds_read
    if (kt + 1 < KT) {
      FWAITV(4);                              // A(kt+1) landed
      FF_CVT_WRITE(nxt);                      // 4 ds_write -> lA[nxt]
    }
    FLGKM0();                                 // frags + writes done
    FF_MFMA();                                // kk0
    if (kt + 2 < KT) FF_LOAD_A((kt + 2) * BK);  // 8 vm
    FF_FRAGS(cur, 1);                         // 12 ds_read
    FLGKM0();                                 // all reads of buf[cur] done
    if (kt + 1 < KT) {
      if (kt + 2 < KT) { FWAITV(8); }         // B(kt+1) landed
      else             { FWAITV(0); }         // tail drain
      FBARF();                                // tile kt+1 ready; buf[cur] free
      if (kt + 2 < KT) FF_STAGE_B(cur, (kt + 2) * BK);
    }
    FF_MFMA();                                // kk1
  }

  // epilogue: bias+relu -> fp8 e4m3
#pragma unroll
  for (int mt = 0; mt < 4; ++mt) {
    int rowb = tm + wr * 128 + mt * 32 + 4 * (lane >> 5);
#pragma unroll
    for (int nt = 0; nt < 2; ++nt) {
      int col = tn + wc * 64 + nt * 32 + l31;
      float bv = bias[col];
#pragma unroll
      for (int reg = 0; reg < 16; ++reg) {
        int row = rowb + (reg & 3) + 8 * (reg >> 2);
        float v = fmaxf(acc[mt][nt][reg] + bv, 0.0f);
        Out[(size_t)row * 768 + col] = f2e4m3(v);
      }
    }
  }
#undef FF_LOAD_A
#undef FF_CVT_WRITE
#undef FF_STAGE_B
#undef FF_FRAGS
#undef FF_MFMA
}

// ======== gemm_sim: sim[b] = P8p[b] @ P8a[b]^T (MX-scaled fp8 MFMA) =========
// 256x128 tile, 8 waves 4Mx2N (64x64/wave via 2x2 frags of 32x32),
// mfma_scale_f32_32x32x64_f8f6f4 with unit e8m0 scales (0x7F = 2^0).
// LDS layout/staging/swizzle/ledger identical to round 14 (proven).
__global__ __launch_bounds__(512, 4)
void gemm_sim(const unsigned char* __restrict__ A, const unsigned char* __restrict__ B,
              float* __restrict__ C) {
  constexpr int BK = 64, KT = 12, LD = 2048;  // K = 768 (BK elems = bytes)
  __shared__ __align__(16) unsigned char lA[2][256 * BK];   // 16 KB per buf
  __shared__ __align__(16) unsigned char lB[2][128 * BK];   // 8 KB per buf

  // T1: XCD-chunked swizzle (2048 = 8 * 256, bijective).
  const int bid  = blockIdx.x;                // 0..2047
  const int virt = (bid & 7) * 256 + (bid >> 3);
  const int bz   = virt >> 7;                 // 0..15 batch
  const int rem  = virt & 127;
  const int by   = rem >> 4;                  // 0..7  M-tile (256 rows)
  const int bx   = rem & 15;                  // 0..15 N-tile (128 rows)

  const int tid  = threadIdx.x;
  const int lane = tid & 63;
  const int w    = tid >> 6;                  // 0..7
  const int wr   = w >> 1;                    // 0..3  (M quarter: 64 rows)
  const int wc   = w & 1;                     // 0..1  (N half: 64 cols)
  const int tm   = by * 256;
  const int tn   = bx * 128;

  const unsigned char* Ab = A + (size_t)bz * LD * 768 + (size_t)tm * 768;
  const unsigned char* Bb = B + (size_t)bz * LD * 768 + (size_t)tn * 768;

  const int l31  = lane & 31;                 // fragment row within 32
  const int kq32 = (lane >> 5) * 32;          // byte base of lane's 32B k-slice
  const int arow = wr * 64 + l31;             // A row base (0..255)
  const int brow = wc * 64 + l31;             // B row base (0..127)
  // frag rows step by 32 -> swizzle constant per lane (hoisted; 32/2=16, &3 inv):
  const int swA  = ((arow >> 1) & 3) << 4;
  const int swB  = ((brow >> 1) & 3) << 4;

  // stage one K-tile: A 16KB (2 rounds) + B 8KB (1 round), pre-swizzled src
#define STAGE(buf, k0)                                                        \
  {                                                                           \
    _Pragma("unroll")                                                         \
    for (int _j = 0; _j < 2; ++_j) {                                          \
      int _c   = _j * 512 + tid;                                              \
      int _row = _c >> 2;                                                     \
      int _cb  = ((_c & 3) * 16) ^ (((_row >> 1) & 3) << 4);                  \
      async_copy16((char*)lA[buf] + _j * 8192 + w * 1024,                     \
                   Ab + (size_t)_row * 768 + (k0) + _cb);                     \
    }                                                                         \
    {                                                                         \
      int _row = tid >> 2;                                                    \
      int _cb  = ((tid & 3) * 16) ^ (((_row >> 1) & 3) << 4);                 \
      async_copy16((char*)lB[buf] + w * 1024,                                 \
                   Bb + (size_t)_row * 768 + (k0) + _cb);                     \
    }                                                                         \
  }

  // per frag: 32 contiguous k-bytes (2 x ds_read_b128, swizzled per 16B half)
#define LOAD_FRAGS_ALL(buf)                                                   \
  {                                                                           \
    const char* _bA = (const char*)lA[buf];                                   \
    const char* _bB = (const char*)lB[buf];                                   \
    _Pragma("unroll")                                                         \
    for (int _mt = 0; _mt < 2; ++_mt) {                                       \
      const char* _r = _bA + (arow + _mt * 32) * BK;                          \
      int4v _lo = *(const int4v*)(_r + ((kq32 + 0)  ^ swA));                  \
      int4v _hi = *(const int4v*)(_r + ((kq32 + 16) ^ swA));                  \
      af[_mt][0] = _lo[0]; af[_mt][1] = _lo[1];                               \
      af[_mt][2] = _lo[2]; af[_mt][3] = _lo[3];                               \
      af[_mt][4] = _hi[0]; af[_mt][5] = _hi[1];                               \
      af[_mt][6] = _hi[2]; af[_mt][7] = _hi[3];                               \
    }                                                                         \
    _Pragma("unroll")                                                         \
    for (int _nt = 0; _nt < 2; ++_nt) {                                       \
      const char* _r = _bB + (brow + _nt * 32) * BK;                          \
      int4v _lo = *(const int4v*)(_r + ((kq32 + 0)  ^ swB));                  \
      int4v _hi = *(const int4v*)(_r + ((kq32 + 16) ^ swB));                  \
      bg[_nt][0] = _lo[0]; bg[_nt][1] = _lo[1];                               \
      bg[_nt][2] = _lo[2]; bg[_nt][3] = _lo[3];                               \
      bg[_nt][4] = _hi[0]; bg[_nt][5] = _hi[1];                               \
      bg[_nt][6] = _hi[2]; bg[_nt][7] = _hi[3];                               \
    }                                                                         \
  }

  // 4 scaled MFMA, unit scales (e8m0 0x7F = 2^0); fmt 0 = fp8 e4m3 both sides
#define MFMA_ALL()                                                            \
  {                                                                           \
    __builtin_amdgcn_s_setprio(1);                                            \
    _Pragma("unroll")                                                         \
    for (int _mt = 0; _mt < 2; ++_mt)                                         \
      _Pragma("unroll")                                                       \
      for (int _nt = 0; _nt < 2; ++_nt)                                       \
        acc[_mt][_nt] = __builtin_amdgcn_mfma_scale_f32_32x32x64_f8f6f4(      \
            af[_mt], bg[_nt], acc[_mt][_nt], 0, 0, 0, 0x7F, 0, 0x7F);         \
    __builtin_amdgcn_s_setprio(0);                                            \
  }

  f32x16 acc[2][2] = {};
  int8v af[2], bg[2];

  STAGE(0, 0);
  STAGE(1, BK);                               // vm out: 6

  int cur = 0;
  for (int kt = 0; kt < KT; ++kt) {
    if (kt < KT - 1) { WAITV3(); } else { WAITV0(); }   // tile kt landed (own)
    BAR();                                              // landed for everyone

    LOAD_FRAGS_ALL(cur);                      // 8 ds_read_b128
    WAITL();                                  // all reads of buf[cur] done
    BAR();                                    // done for everyone -> buf free
    if (kt < KT - 2) STAGE(cur, (kt + 2) * BK);  // overlapped with MFMAs
    MFMA_ALL();                               // 4 x mfma_scale 32x32x64

    cur ^= 1;
  }

  // epilogue: 32x32 C/D layout col=lane&31, row=(reg&3)+8*(reg>>2)+4*(lane>>5)
  float* Cb = C + (size_t)bz * LD * LD;
#pragma unroll
  for (int mt = 0; mt < 2; ++mt) {
    int rowb = tm + wr * 64 + mt * 32 + 4 * (lane >> 5);
#pragma unroll
    for (int nt = 0; nt < 2; ++nt) {
      int col = tn + wc * 64 + nt * 32 + l31;
#pragma unroll
      for (int reg = 0; reg < 16; ++reg) {
        int row = rowb + (reg & 3) + 8 * (reg >> 2);
        Cb[(size_t)row * LD + col] = acc[mt][nt][reg];
      }
    }
  }
#undef STAGE
#undef LOAD_FRAGS_ALL
#undef MFMA_ALL
}

extern "C" void kernel_launch(void* const* d_in, const int* in_sizes, int n_in,
                              void* d_out, int out_size, void* d_ws, size_t ws_size,
                              hipStream_t stream) {
  const float* seq_prev  = (const float*)d_in[0];  // [16][2048][768]
  const float* seq_after = (const float*)d_in[1];  // [16][2048][768]
  const float* W         = (const float*)d_in[2];  // [768][768] (in,out)
  const float* bias      = (const float*)d_in[3];  // [768]
  float* out             = (float*)d_out;          // [16][2048][2048] fp32

  char* ws           = (char*)d_ws;
  short* Wt          = (short*)ws;                 // 768*768*2 = 1179648 B
  unsigned char* P8  = (unsigned char*)(ws + 1179648);  // 65536*768 fp8 = 48 MB

  constexpr int NSEQ = 16 * 2048 * 768;            // elems (=bytes in fp8)

  // 1. W transpose + convert
  wt_kernel<<<768 * 768 / 256, 256, 0, stream>>>(W, Wt);

  // 2. feed-forward + relu -> fp8 (768 blocks, XCD-swizzled)
  gemm_ff<<<768, 512, 0, stream>>>(seq_prev, seq_after, Wt, bias, P8);

  // 3. batched similarity in MX-fp8 (2048 blocks, XCD-swizzled)
  gemm_sim<<<2048, 512, 0, stream>>>(P8, P8 + NSEQ, out);
}